// Round 1
// baseline (57.423 us; speedup 1.0000x reference)
//
#include <hip/hip_runtime.h>
#include <cmath>

#define NCLS 80
#define NB 16
#define NP 8400
#define NG 64
#define CHUNKS 33            // ceil(8400/256)
#define NBLK_B (NB * CHUNKS) // 528
#define NBLK_A 1024
#define EPSF 1e-7f

__device__ __forceinline__ float softplus_bce(float l) {
    // max(l,0) + log1p(exp(-|l|))
    return fmaxf(l, 0.f) + log1pf(expf(-fabsf(l)));
}

__device__ __forceinline__ float sanitize_box(float x) {
    // nan_to_num(nan=0, posinf=1000, neginf=0) then clip [-1000,1000]
    if (isnan(x)) return 0.f;
    if (isinf(x)) x = (x > 0.f) ? 1000.f : 0.f;
    return fminf(fmaxf(x, -1000.f), 1000.f);
}

// ---------------- Kernel A: sum of softplus over all pred_cls ----------------
__global__ __launch_bounds__(256) void kA_cls_softplus(
    const float4* __restrict__ cls4, int n4, double* __restrict__ part)
{
    double acc = 0.0;
    for (int i = blockIdx.x * blockDim.x + threadIdx.x; i < n4;
         i += gridDim.x * blockDim.x) {
        float4 v = cls4[i];
        float s = softplus_bce(v.x) + softplus_bce(v.y) +
                  softplus_bce(v.z) + softplus_bce(v.w);
        acc += (double)s;
    }
    __shared__ double sh[4];
    for (int off = 32; off; off >>= 1) acc += __shfl_down(acc, off, 64);
    if ((threadIdx.x & 63) == 0) sh[threadIdx.x >> 6] = acc;
    __syncthreads();
    if (threadIdx.x == 0) part[blockIdx.x] = sh[0] + sh[1] + sh[2] + sh[3];
}

// ---------------- Kernel B: per-point assignment + CIoU + obj BCE ----------------
__global__ __launch_bounds__(256) void kB_assign(
    const float* __restrict__ pred_cls, const float* __restrict__ pred_obj,
    const float4* __restrict__ decoded, const float2* __restrict__ points,
    const float* __restrict__ strides, const float4* __restrict__ gt_boxes,
    const int* __restrict__ gt_labels, double* __restrict__ part)
{
    const int b = blockIdx.x / CHUNKS;
    const int chunk = blockIdx.x % CHUNKS;
    const int p = chunk * 256 + threadIdx.x;

    __shared__ float4 gbox[NG];
    __shared__ float garea[NG];
    __shared__ int glab[NG];
    if (threadIdx.x < NG) {
        float4 gb = gt_boxes[b * NG + threadIdx.x];
        gbox[threadIdx.x] = gb;
        garea[threadIdx.x] = (gb.z - gb.x) * (gb.w - gb.y);
        glab[threadIdx.x] = gt_labels[b * NG + threadIdx.x];
    }
    __syncthreads();

    float cnt_fg = 0.f, sum_box = 0.f, sum_obj = 0.f, sum_corr = 0.f;

    if (p < NP) {
        float2 pt = points[p];
        const float px = pt.x, py = pt.y;
        const float s = strides[p];
        const float r = s * 2.5f;
        const float fit_thr = s * 8.0f;

        unsigned long long match = 0ull, fallback = 0ull;
        #pragma unroll 4
        for (int g = 0; g < NG; ++g) {
            float4 gb = gbox[g];
            float d0 = px - gb.x, d1 = py - gb.y, d2 = gb.z - px, d3 = gb.w - py;
            float dmin = fminf(fminf(d0, d1), fminf(d2, d3));
            float dmax = fmaxf(fmaxf(d0, d1), fmaxf(d2, d3));
            bool ib = dmin > 0.f;
            float cx = (gb.x + gb.z) * 0.5f, cy = (gb.y + gb.w) * 0.5f;
            float c0 = px - (cx - r), c1 = py - (cy - r);
            float c2 = cx + r - px, c3 = cy + r - py;
            float cmin = fminf(fminf(c0, c1), fminf(c2, c3));
            bool fb = ib && (cmin > 0.f);
            bool m = fb && (dmax <= fit_thr);
            unsigned long long bit = 1ull << g;
            if (m) match |= bit;
            if (fb) fallback |= bit;
        }
        unsigned long long mask = match ? match : fallback;

        float lo = pred_obj[b * NP + p];
        float tobj = 0.f;

        if (mask) {
            // argmin area, first-index tie-break (matches jnp.argmin)
            int best = 0; float bestA = INFINITY;
            unsigned long long mm = mask;
            while (mm) {
                int g = __ffsll((long long)mm) - 1;
                mm &= mm - 1;
                float a = garea[g];
                if (a < bestA) { bestA = a; best = g; }
            }
            cnt_fg = 1.f;

            // sanitize predicted box
            float4 db = decoded[(size_t)b * NP + p];
            float x1 = sanitize_box(db.x);
            float y1 = sanitize_box(db.y);
            float x2 = fmaxf(x1 + 0.001f, sanitize_box(db.z));
            float y2 = fmaxf(y1 + 0.001f, sanitize_box(db.w));

            float4 g4 = gbox[best];
            float gx1 = g4.x, gy1 = g4.y, gx2 = g4.z, gy2 = g4.w;

            float w1 = x2 - x1, h1 = y2 - y1;
            float w2 = gx2 - gx1, h2 = gy2 - gy1;
            float iw = fmaxf(fminf(x2, gx2) - fmaxf(x1, gx1), 0.f);
            float ih = fmaxf(fminf(y2, gy2) - fmaxf(y1, gy1), 0.f);
            float inter = iw * ih;
            float uni = w1 * h1 + w2 * h2 - inter + EPSF;
            float iou = inter / uni;
            float cw = fmaxf(x2, gx2) - fminf(x1, gx1);
            float ch = fmaxf(y2, gy2) - fminf(y1, gy1);
            float c2d = cw * cw + ch * ch + EPSF;
            float dx = x1 + x2 - gx1 - gx2, dy = y1 + y2 - gy1 - gy2;
            float rho2 = (dx * dx + dy * dy) * 0.25f;
            float da = atanf(w2 / (h2 + EPSF)) - atanf(w1 / (h1 + EPSF));
            float v = 0.40528473456935108577551785283891f * da * da; // 4/pi^2
            float alpha = v / (1.f - iou + v + EPSF);
            float ciou = 1.f - (iou - rho2 / c2d - alpha * v);
            if (isnan(ciou) || isinf(ciou)) ciou = 1.f;
            ciou = fminf(fmaxf(ciou, 0.f), 2.f);
            sum_box = ciou;
            tobj = fminf(fmaxf(1.f - ciou, 0.f), 1.f);

            // cls BCE correction: logit at matched label
            sum_corr = pred_cls[((size_t)b * NP + p) * NCLS + glab[best]];
        }
        sum_obj = softplus_bce(lo) - lo * tobj;
    }

    // block reduce 4 values -> per-block partials (SoA layout)
    __shared__ double sh4[4][4];
    double vals[4] = {(double)cnt_fg, (double)sum_box, (double)sum_obj, (double)sum_corr};
    for (int k = 0; k < 4; ++k) {
        double v = vals[k];
        for (int off = 32; off; off >>= 1) v += __shfl_down(v, off, 64);
        if ((threadIdx.x & 63) == 0) sh4[k][threadIdx.x >> 6] = v;
    }
    __syncthreads();
    if (threadIdx.x == 0) {
        for (int k = 0; k < 4; ++k)
            part[k * NBLK_B + blockIdx.x] =
                sh4[k][0] + sh4[k][1] + sh4[k][2] + sh4[k][3];
    }
}

// ---------------- Kernel C: deterministic final reduce + combine ----------------
__global__ __launch_bounds__(256) void kC_finalize(
    const double* __restrict__ clsPart, const double* __restrict__ bPart,
    float* __restrict__ out)
{
    double acc[5] = {0, 0, 0, 0, 0};
    for (int i = threadIdx.x; i < NBLK_A; i += 256) acc[0] += clsPart[i];
    for (int k = 0; k < 4; ++k)
        for (int i = threadIdx.x; i < NBLK_B; i += 256)
            acc[1 + k] += bPart[k * NBLK_B + i];

    __shared__ double sh[4];
    __shared__ double tot[5];
    for (int k = 0; k < 5; ++k) {
        double v = acc[k];
        for (int off = 32; off; off >>= 1) v += __shfl_down(v, off, 64);
        __syncthreads();
        if ((threadIdx.x & 63) == 0) sh[threadIdx.x >> 6] = v;
        __syncthreads();
        if (threadIdx.x == 0) tot[k] = sh[0] + sh[1] + sh[2] + sh[3];
    }
    __syncthreads();
    if (threadIdx.x == 0) {
        double cls_sum = tot[0], fg_sum = tot[1], box_sum = tot[2],
               obj_sum = tot[3], corr_sum = tot[4];

        float loss_cls = (float)((cls_sum - corr_sum) /
                                 (double)((size_t)NB * NP * NCLS));
        if (isnan(loss_cls)) loss_cls = 0.f;
        loss_cls = fminf(loss_cls, 10.f);

        float numfg = (float)fg_sum;
        float norm = fmaxf(numfg, 1.f);
        float loss_box = (float)box_sum / norm;
        if (isnan(loss_box)) loss_box = 0.f;
        loss_box = fminf(loss_box, 10.f);

        float loss_obj = (float)(obj_sum / (double)(NB * NP));
        if (isnan(loss_obj)) loss_obj = 0.f;
        loss_obj = fminf(loss_obj, 10.f);

        // CLS_W=0.5, BOX_W*WARMUP = 7.5*(1/3) = 2.5, OBJ_W=1
        float total = 0.5f * loss_cls + 2.5f * loss_box + loss_obj;
        if (isnan(total)) total = 0.f;
        total = fminf(total, 10.f);

        out[0] = total; out[1] = loss_cls; out[2] = loss_box; out[3] = loss_obj;
    }
}

extern "C" void kernel_launch(void* const* d_in, const int* in_sizes, int n_in,
                              void* d_out, int out_size, void* d_ws, size_t ws_size,
                              hipStream_t stream) {
    const float*  pred_cls  = (const float*)d_in[0];
    // d_in[1] = pred_box: dead in the reference, never read
    const float*  pred_obj  = (const float*)d_in[2];
    const float4* decoded   = (const float4*)d_in[3];
    const float2* points    = (const float2*)d_in[4];
    const float*  strides   = (const float*)d_in[5];
    const float4* gt_boxes  = (const float4*)d_in[6];
    const int*    gt_labels = (const int*)d_in[7];

    double* ws      = (double*)d_ws;
    double* clsPart = ws;            // NBLK_A doubles
    double* bPart   = ws + NBLK_A;   // 4*NBLK_B doubles

    const int n4 = NB * NP * NCLS / 4; // 2,688,000 float4s, exact

    kA_cls_softplus<<<NBLK_A, 256, 0, stream>>>(
        (const float4*)pred_cls, n4, clsPart);
    kB_assign<<<NBLK_B, 256, 0, stream>>>(
        pred_cls, pred_obj, decoded, points, strides, gt_boxes, gt_labels, bPart);
    kC_finalize<<<1, 256, 0, stream>>>(clsPart, bPart, (float*)d_out);
}

// Round 2
// 34.902 us; speedup vs baseline: 1.6453x; 1.6453x over previous
//
#include <hip/hip_runtime.h>
#include <cmath>

#define NCLS 80
#define NB 16
#define NP 8400
#define NG 64
#define CHUNKS 33            // ceil(8400/256)
#define NBLK_B (NB * CHUNKS) // 528
#define NBLK_A 2048
#define EPSF 1e-7f

// Fast softplus-BCE: max(l,0) + log1p(exp(-|l|)) using native v_exp/v_log.
// Native ops are ~2ulp; output is a mean over 10.7M elems -> error ~1e-6.
__device__ __forceinline__ float softplus_bce(float l) {
    float a = fabsf(l);
    float t = __expf(-a);              // v_exp_f32
    return fmaxf(l, 0.f) + __logf(1.f + t);  // v_log_f32
}

__device__ __forceinline__ float sanitize_box(float x) {
    // nan_to_num(nan=0, posinf=1000, neginf=0) then clip [-1000,1000]
    if (isnan(x)) return 0.f;
    if (isinf(x)) x = (x > 0.f) ? 1000.f : 0.f;
    return fminf(fmaxf(x, -1000.f), 1000.f);
}

// ---------------- Kernel A: sum of softplus over all pred_cls ----------------
__global__ __launch_bounds__(256) void kA_cls_softplus(
    const float4* __restrict__ cls4, int n4, double* __restrict__ part)
{
    double acc = 0.0;
    for (int i = blockIdx.x * blockDim.x + threadIdx.x; i < n4;
         i += gridDim.x * blockDim.x) {
        float4 v = cls4[i];
        float s = softplus_bce(v.x) + softplus_bce(v.y) +
                  softplus_bce(v.z) + softplus_bce(v.w);
        acc += (double)s;
    }
    __shared__ double sh[4];
    for (int off = 32; off; off >>= 1) acc += __shfl_down(acc, off, 64);
    if ((threadIdx.x & 63) == 0) sh[threadIdx.x >> 6] = acc;
    __syncthreads();
    if (threadIdx.x == 0) part[blockIdx.x] = sh[0] + sh[1] + sh[2] + sh[3];
}

// ---------------- Kernel B: per-point assignment + CIoU + obj BCE ----------------
__global__ __launch_bounds__(256) void kB_assign(
    const float* __restrict__ pred_cls, const float* __restrict__ pred_obj,
    const float4* __restrict__ decoded, const float2* __restrict__ points,
    const float* __restrict__ strides, const float4* __restrict__ gt_boxes,
    const int* __restrict__ gt_labels, double* __restrict__ part)
{
    const int b = blockIdx.x / CHUNKS;
    const int chunk = blockIdx.x % CHUNKS;
    const int p = chunk * 256 + threadIdx.x;

    __shared__ float4 gbox[NG];
    __shared__ float garea[NG];
    __shared__ int glab[NG];
    if (threadIdx.x < NG) {
        float4 gb = gt_boxes[b * NG + threadIdx.x];
        gbox[threadIdx.x] = gb;
        garea[threadIdx.x] = (gb.z - gb.x) * (gb.w - gb.y);
        glab[threadIdx.x] = gt_labels[b * NG + threadIdx.x];
    }
    __syncthreads();

    float cnt_fg = 0.f, sum_box = 0.f, sum_obj = 0.f, sum_corr = 0.f;

    if (p < NP) {
        float2 pt = points[p];
        const float px = pt.x, py = pt.y;
        const float s = strides[p];
        const float r = s * 2.5f;
        const float fit_thr = s * 8.0f;

        unsigned long long match = 0ull, fallback = 0ull;
        #pragma unroll 4
        for (int g = 0; g < NG; ++g) {
            float4 gb = gbox[g];
            float d0 = px - gb.x, d1 = py - gb.y, d2 = gb.z - px, d3 = gb.w - py;
            float dmin = fminf(fminf(d0, d1), fminf(d2, d3));
            float dmax = fmaxf(fmaxf(d0, d1), fmaxf(d2, d3));
            bool ib = dmin > 0.f;
            float cx = (gb.x + gb.z) * 0.5f, cy = (gb.y + gb.w) * 0.5f;
            float c0 = px - (cx - r), c1 = py - (cy - r);
            float c2 = cx + r - px, c3 = cy + r - py;
            float cmin = fminf(fminf(c0, c1), fminf(c2, c3));
            bool fb = ib && (cmin > 0.f);
            bool m = fb && (dmax <= fit_thr);
            unsigned long long bit = 1ull << g;
            if (m) match |= bit;
            if (fb) fallback |= bit;
        }
        unsigned long long mask = match ? match : fallback;

        float lo = pred_obj[b * NP + p];
        float tobj = 0.f;

        if (mask) {
            // argmin area, first-index tie-break (matches jnp.argmin)
            int best = 0; float bestA = INFINITY;
            unsigned long long mm = mask;
            while (mm) {
                int g = __ffsll((long long)mm) - 1;
                mm &= mm - 1;
                float a = garea[g];
                if (a < bestA) { bestA = a; best = g; }
            }
            cnt_fg = 1.f;

            // sanitize predicted box
            float4 db = decoded[(size_t)b * NP + p];
            float x1 = sanitize_box(db.x);
            float y1 = sanitize_box(db.y);
            float x2 = fmaxf(x1 + 0.001f, sanitize_box(db.z));
            float y2 = fmaxf(y1 + 0.001f, sanitize_box(db.w));

            float4 g4 = gbox[best];
            float gx1 = g4.x, gy1 = g4.y, gx2 = g4.z, gy2 = g4.w;

            float w1 = x2 - x1, h1 = y2 - y1;
            float w2 = gx2 - gx1, h2 = gy2 - gy1;
            float iw = fmaxf(fminf(x2, gx2) - fmaxf(x1, gx1), 0.f);
            float ih = fmaxf(fminf(y2, gy2) - fmaxf(y1, gy1), 0.f);
            float inter = iw * ih;
            float uni = w1 * h1 + w2 * h2 - inter + EPSF;
            float iou = inter / uni;
            float cw = fmaxf(x2, gx2) - fminf(x1, gx1);
            float ch = fmaxf(y2, gy2) - fminf(y1, gy1);
            float c2d = cw * cw + ch * ch + EPSF;
            float dx = x1 + x2 - gx1 - gx2, dy = y1 + y2 - gy1 - gy2;
            float rho2 = (dx * dx + dy * dy) * 0.25f;
            float da = atanf(w2 / (h2 + EPSF)) - atanf(w1 / (h1 + EPSF));
            float v = 0.40528473456935108577551785283891f * da * da; // 4/pi^2
            float alpha = v / (1.f - iou + v + EPSF);
            float ciou = 1.f - (iou - rho2 / c2d - alpha * v);
            if (isnan(ciou) || isinf(ciou)) ciou = 1.f;
            ciou = fminf(fmaxf(ciou, 0.f), 2.f);
            sum_box = ciou;
            tobj = fminf(fmaxf(1.f - ciou, 0.f), 1.f);

            // cls BCE correction: logit at matched label
            sum_corr = pred_cls[((size_t)b * NP + p) * NCLS + glab[best]];
        }
        sum_obj = softplus_bce(lo) - lo * tobj;
    }

    // block reduce 4 values -> per-block partials (SoA layout)
    __shared__ double sh4[4][4];
    double vals[4] = {(double)cnt_fg, (double)sum_box, (double)sum_obj, (double)sum_corr};
    for (int k = 0; k < 4; ++k) {
        double v = vals[k];
        for (int off = 32; off; off >>= 1) v += __shfl_down(v, off, 64);
        if ((threadIdx.x & 63) == 0) sh4[k][threadIdx.x >> 6] = v;
    }
    __syncthreads();
    if (threadIdx.x == 0) {
        for (int k = 0; k < 4; ++k)
            part[k * NBLK_B + blockIdx.x] =
                sh4[k][0] + sh4[k][1] + sh4[k][2] + sh4[k][3];
    }
}

// ---------------- Kernel C: deterministic final reduce + combine ----------------
__global__ __launch_bounds__(256) void kC_finalize(
    const double* __restrict__ clsPart, const double* __restrict__ bPart,
    float* __restrict__ out)
{
    double acc[5] = {0, 0, 0, 0, 0};
    for (int i = threadIdx.x; i < NBLK_A; i += 256) acc[0] += clsPart[i];
    for (int k = 0; k < 4; ++k)
        for (int i = threadIdx.x; i < NBLK_B; i += 256)
            acc[1 + k] += bPart[k * NBLK_B + i];

    __shared__ double sh[4];
    __shared__ double tot[5];
    for (int k = 0; k < 5; ++k) {
        double v = acc[k];
        for (int off = 32; off; off >>= 1) v += __shfl_down(v, off, 64);
        __syncthreads();
        if ((threadIdx.x & 63) == 0) sh[threadIdx.x >> 6] = v;
        __syncthreads();
        if (threadIdx.x == 0) tot[k] = sh[0] + sh[1] + sh[2] + sh[3];
    }
    __syncthreads();
    if (threadIdx.x == 0) {
        double cls_sum = tot[0], fg_sum = tot[1], box_sum = tot[2],
               obj_sum = tot[3], corr_sum = tot[4];

        float loss_cls = (float)((cls_sum - corr_sum) /
                                 (double)((size_t)NB * NP * NCLS));
        if (isnan(loss_cls)) loss_cls = 0.f;
        loss_cls = fminf(loss_cls, 10.f);

        float numfg = (float)fg_sum;
        float norm = fmaxf(numfg, 1.f);
        float loss_box = (float)box_sum / norm;
        if (isnan(loss_box)) loss_box = 0.f;
        loss_box = fminf(loss_box, 10.f);

        float loss_obj = (float)(obj_sum / (double)(NB * NP));
        if (isnan(loss_obj)) loss_obj = 0.f;
        loss_obj = fminf(loss_obj, 10.f);

        // CLS_W=0.5, BOX_W*WARMUP = 7.5*(1/3) = 2.5, OBJ_W=1
        float total = 0.5f * loss_cls + 2.5f * loss_box + loss_obj;
        if (isnan(total)) total = 0.f;
        total = fminf(total, 10.f);

        out[0] = total; out[1] = loss_cls; out[2] = loss_box; out[3] = loss_obj;
    }
}

extern "C" void kernel_launch(void* const* d_in, const int* in_sizes, int n_in,
                              void* d_out, int out_size, void* d_ws, size_t ws_size,
                              hipStream_t stream) {
    const float*  pred_cls  = (const float*)d_in[0];
    // d_in[1] = pred_box: dead in the reference, never read
    const float*  pred_obj  = (const float*)d_in[2];
    const float4* decoded   = (const float4*)d_in[3];
    const float2* points    = (const float2*)d_in[4];
    const float*  strides   = (const float*)d_in[5];
    const float4* gt_boxes  = (const float4*)d_in[6];
    const int*    gt_labels = (const int*)d_in[7];

    double* ws      = (double*)d_ws;
    double* clsPart = ws;            // NBLK_A doubles
    double* bPart   = ws + NBLK_A;   // 4*NBLK_B doubles

    const int n4 = NB * NP * NCLS / 4; // 2,688,000 float4s, exact

    kA_cls_softplus<<<NBLK_A, 256, 0, stream>>>(
        (const float4*)pred_cls, n4, clsPart);
    kB_assign<<<NBLK_B, 256, 0, stream>>>(
        pred_cls, pred_obj, decoded, points, strides, gt_boxes, gt_labels, bPart);
    kC_finalize<<<1, 256, 0, stream>>>(clsPart, bPart, (float*)d_out);
}